// Round 1
// baseline (572.240 us; speedup 1.0000x reference)
//
#include <hip/hip_runtime.h>
#include <hip/hip_bf16.h>
#include <cstddef>

// Problem constants
#define NB 2        // batch
#define QN 12240    // queries (= S)
#define SN 12240    // source spatial total
#define DD 256      // model dim
#define MH 8        // heads
#define LK16 16     // L*K
#define DVC 32      // value channels per head

// ---------------------------------------------------------------------------
// Generic tiled fp32 GEMM: C = A(M,K) @ B(K,N) + bias(N), row-major.
// BM=64, BN=64, BK=16, 256 threads, 4x4 micro-tile per thread.
// ---------------------------------------------------------------------------
__global__ __launch_bounds__(256) void gemm_bias_kernel(
    const float* __restrict__ A, const float* __restrict__ B,
    const float* __restrict__ bias, float* __restrict__ C,
    int Mdim, int Ndim, int Kdim)
{
    __shared__ __align__(16) float As[16][68];
    __shared__ __align__(16) float Bs[16][68];

    const int tid  = threadIdx.x;
    const int row0 = blockIdx.y * 64;
    const int col0 = blockIdx.x * 64;
    const int ty = tid >> 4;      // 0..15
    const int tx = tid & 15;      // 0..15

    const int arow = tid >> 2;          // 0..63
    const int ak4  = (tid & 3) << 2;    // 0,4,8,12
    const int brow = tid >> 4;          // 0..15
    const int bcol4 = (tid & 15) << 2;  // 0..60

    float acc[4][4];
    #pragma unroll
    for (int i = 0; i < 4; i++)
        #pragma unroll
        for (int j = 0; j < 4; j++) acc[i][j] = 0.f;

    for (int k0 = 0; k0 < Kdim; k0 += 16) {
        float4 av;
        const int grow = row0 + arow;
        if (grow < Mdim) {
            av = *(const float4*)(A + (size_t)grow * Kdim + k0 + ak4);
        } else {
            av = make_float4(0.f, 0.f, 0.f, 0.f);
        }
        As[ak4 + 0][arow] = av.x;
        As[ak4 + 1][arow] = av.y;
        As[ak4 + 2][arow] = av.z;
        As[ak4 + 3][arow] = av.w;

        const float4 bv = *(const float4*)(B + (size_t)(k0 + brow) * Ndim + col0 + bcol4);
        *(float4*)&Bs[brow][bcol4] = bv;

        __syncthreads();

        #pragma unroll
        for (int kk = 0; kk < 16; kk++) {
            const float4 a4 = *(const float4*)&As[kk][ty << 2];
            const float4 b4 = *(const float4*)&Bs[kk][tx << 2];
            const float aa[4] = {a4.x, a4.y, a4.z, a4.w};
            const float bb[4] = {b4.x, b4.y, b4.z, b4.w};
            #pragma unroll
            for (int i = 0; i < 4; i++)
                #pragma unroll
                for (int j = 0; j < 4; j++)
                    acc[i][j] += aa[i] * bb[j];
        }
        __syncthreads();
    }

    #pragma unroll
    for (int i = 0; i < 4; i++) {
        const int r = row0 + (ty << 2) + i;
        if (r < Mdim) {
            #pragma unroll
            for (int j = 0; j < 4; j++) {
                const int c = col0 + (tx << 2) + j;
                C[(size_t)r * Ndim + c] = acc[i][j] + bias[c];
            }
        }
    }
}

// ---------------------------------------------------------------------------
// Fused softmax + bilinear sampling. One block per (q, n).
// Thread = (m, dv): m = tid>>5, dv = tid&31. Writes out_mdv into d_out.
// ---------------------------------------------------------------------------
__global__ __launch_bounds__(256) void sample_kernel(
    const float* __restrict__ logits,   // (N*Q, 128)
    const float* __restrict__ off,      // (N*Q, 256) as (M,LK,2)
    const float* __restrict__ geom,     // (N*Q, 4)
    const float* __restrict__ v,        // (N*S, 256) as (s, m*32+dv)
    float* __restrict__ out)            // (N*Q, 256) out_mdv staging
{
    const int q = blockIdx.x;
    const int n = blockIdx.y;
    const int tid = threadIdx.x;
    const int m = tid >> 5;

    __shared__ float l_sm[128];
    __shared__ float o_sm[256];
    __shared__ float g_sm[4];

    const size_t qb = (size_t)n * QN + q;
    if (tid < 128) l_sm[tid] = logits[qb * 128 + tid];
    o_sm[tid] = off[qb * 256 + tid];
    if (tid < 4) g_sm[tid] = geom[qb * 4 + tid];
    __syncthreads();

    // softmax over the 16 points of this head (redundant across dv lanes)
    float mx = -1e30f;
    #pragma unroll
    for (int lk = 0; lk < 16; lk++) mx = fmaxf(mx, l_sm[m * 16 + lk]);
    float wexp[16];
    float ssum = 0.f;
    #pragma unroll
    for (int lk = 0; lk < 16; lk++) {
        wexp[lk] = __expf(l_sm[m * 16 + lk] - mx);
        ssum += wexp[lk];
    }
    const float inv = 1.f / ssum;

    const float cx = g_sm[0], cy = g_sm[1];
    const float sx = g_sm[2] * 0.125f, sy = g_sm[3] * 0.125f;

    const float* vbase = v + (size_t)n * SN * 256 + tid;  // tid == m*32+dv
    float acc = 0.f;

    #pragma unroll
    for (int lk = 0; lk < 16; lk++) {
        const int l = lk >> 2;
        const int Wl = 96 >> l;             // 96,48,24,12 (square levels)
        const int s0 = (l == 0) ? 0 : (l == 1) ? 9216 : (l == 2) ? 11520 : 12096;

        const float px = cx + o_sm[(m * 16 + lk) * 2 + 0] * sx;
        const float py = cy + o_sm[(m * 16 + lk) * 2 + 1] * sy;
        // grid = 2*pos-1; x = (grid+1)*(W/2)-0.5  ==  pos*W - 0.5
        const float x = px * (float)Wl - 0.5f;
        const float y = py * (float)Wl - 0.5f;
        const float xf = floorf(x), yf = floorf(y);
        const int x0 = (int)xf, y0 = (int)yf;
        const float wx = x - xf, wy = y - yf;

        const float w00 = (1.f - wx) * (1.f - wy);
        const float w10 = wx * (1.f - wy);
        const float w01 = (1.f - wx) * wy;
        const float w11 = wx * wy;

        const float* vb = vbase + (size_t)s0 * 256;
        float val = 0.f;
        const bool vx0 = (x0 >= 0) & (x0 < Wl);
        const bool vx1 = (x0 + 1 >= 0) & (x0 + 1 < Wl);
        const bool vy0 = (y0 >= 0) & (y0 < Wl);
        const bool vy1 = (y0 + 1 >= 0) & (y0 + 1 < Wl);
        if (vx0 & vy0) val += w00 * vb[(size_t)(y0 * Wl + x0) * 256];
        if (vx1 & vy0) val += w10 * vb[(size_t)(y0 * Wl + x0 + 1) * 256];
        if (vx0 & vy1) val += w01 * vb[(size_t)((y0 + 1) * Wl + x0) * 256];
        if (vx1 & vy1) val += w11 * vb[(size_t)((y0 + 1) * Wl + x0 + 1) * 256];

        acc += (wexp[lk] * inv) * val;
    }

    out[qb * 256 + tid] = acc;
}

// ---------------------------------------------------------------------------
// Final GEMM, in-place on d_out: out[r,:] = out_mdv[r,:] @ W_out + b_out.
// Each block owns 16 rows exclusively (stages them in LDS before writing),
// so in-place is race-free. 256 threads; thread = output column d.
// ---------------------------------------------------------------------------
__global__ __launch_bounds__(256) void out_gemm_inplace(
    const float* __restrict__ Wout, const float* __restrict__ bout,
    float* __restrict__ out)
{
    __shared__ __align__(16) float A[16][256];
    const int d = threadIdx.x;
    const size_t row0 = (size_t)blockIdx.x * 16;

    #pragma unroll
    for (int r = 0; r < 16; r++) A[r][d] = out[(row0 + r) * 256 + d];
    __syncthreads();

    float acc[16];
    const float bb = bout[d];
    #pragma unroll
    for (int r = 0; r < 16; r++) acc[r] = bb;

    for (int k = 0; k < 256; k += 4) {
        const float w0 = Wout[(size_t)(k + 0) * 256 + d];
        const float w1 = Wout[(size_t)(k + 1) * 256 + d];
        const float w2 = Wout[(size_t)(k + 2) * 256 + d];
        const float w3 = Wout[(size_t)(k + 3) * 256 + d];
        #pragma unroll
        for (int r = 0; r < 16; r++) {
            const float4 a4 = *(const float4*)&A[r][k];
            acc[r] += a4.x * w0 + a4.y * w1 + a4.z * w2 + a4.w * w3;
        }
    }

    __syncthreads();
    #pragma unroll
    for (int r = 0; r < 16; r++) out[(row0 + r) * 256 + d] = acc[r];
}

// ---------------------------------------------------------------------------
extern "C" void kernel_launch(void* const* d_in, const int* in_sizes, int n_in,
                              void* d_out, int out_size, void* d_ws, size_t ws_size,
                              hipStream_t stream)
{
    const float* queries = (const float*)d_in[0];   // (N,Q,256)
    const float* geom    = (const float*)d_in[1];   // (N,Q,4)
    const float* src     = (const float*)d_in[2];   // (N,S,256)
    const float* W_off   = (const float*)d_in[3];   // (256,256)
    const float* b_off   = (const float*)d_in[4];   // (256,)
    const float* W_attn  = (const float*)d_in[5];   // (256,128)
    const float* b_attn  = (const float*)d_in[6];   // (128,)
    const float* W_val   = (const float*)d_in[7];   // (256,256)
    const float* b_val   = (const float*)d_in[8];   // (256,)
    const float* W_out   = (const float*)d_in[9];   // (256,256)
    const float* b_out   = (const float*)d_in[10];  // (256,)
    float* out = (float*)d_out;
    float* ws  = (float*)d_ws;

    const int ROWS = NB * QN;  // 24480
    float* v_ws      = ws;                      // 24480*256 = 6,266,880 floats
    float* logits_ws = ws + (size_t)6266880;    // 24480*128 = 3,133,440 floats
    float* off_ws    = ws + (size_t)9400320;    // 24480*256 = 6,266,880 floats
    // total ws use: 15,667,200 floats = 62.7 MB

    dim3 blk(256);
    const int gy = (ROWS + 63) / 64;  // 383

    // v = src @ W_val + b_val          (24480 x 256)
    gemm_bias_kernel<<<dim3(4, gy), blk, 0, stream>>>(src, W_val, b_val, v_ws, ROWS, 256, 256);
    // logits = q @ W_attn + b_attn     (24480 x 128)
    gemm_bias_kernel<<<dim3(2, gy), blk, 0, stream>>>(queries, W_attn, b_attn, logits_ws, ROWS, 128, 256);
    // off = q @ W_off + b_off          (24480 x 256)
    gemm_bias_kernel<<<dim3(4, gy), blk, 0, stream>>>(queries, W_off, b_off, off_ws, ROWS, 256, 256);
    // softmax + bilinear sample -> out_mdv (staged in d_out)
    sample_kernel<<<dim3(QN, NB), blk, 0, stream>>>(logits_ws, off_ws, geom, v_ws, out);
    // out = out_mdv @ W_out + b_out (in-place on d_out)
    out_gemm_inplace<<<dim3(ROWS / 16), blk, 0, stream>>>(W_out, b_out, out);
}

// Round 2
// 394.507 us; speedup vs baseline: 1.4505x; 1.4505x over previous
//
#include <hip/hip_runtime.h>
#include <hip/hip_bf16.h>
#include <cstddef>

// Problem constants
#define NB 2        // batch
#define QN 12240    // queries (= S)
#define SN 12240    // source spatial total
#define DD 256      // model dim
#define MH 8        // heads
#define LK16 16     // L*K
#define DVC 32      // value channels per head

// ---------------------------------------------------------------------------
// Generic tiled fp32 GEMM: C = A(M,K) @ B(K,N) + bias(N), row-major.
// BM=64, BN=64, BK=16, 256 threads, 4x4 micro-tile per thread.
// ---------------------------------------------------------------------------
__global__ __launch_bounds__(256) void gemm_bias_kernel(
    const float* __restrict__ A, const float* __restrict__ B,
    const float* __restrict__ bias, float* __restrict__ C,
    int Mdim, int Ndim, int Kdim)
{
    __shared__ __align__(16) float As[16][68];
    __shared__ __align__(16) float Bs[16][68];

    const int tid  = threadIdx.x;
    const int row0 = blockIdx.y * 64;
    const int col0 = blockIdx.x * 64;
    const int ty = tid >> 4;      // 0..15
    const int tx = tid & 15;      // 0..15

    const int arow = tid >> 2;          // 0..63
    const int ak4  = (tid & 3) << 2;    // 0,4,8,12
    const int brow = tid >> 4;          // 0..15
    const int bcol4 = (tid & 15) << 2;  // 0..60

    float acc[4][4];
    #pragma unroll
    for (int i = 0; i < 4; i++)
        #pragma unroll
        for (int j = 0; j < 4; j++) acc[i][j] = 0.f;

    for (int k0 = 0; k0 < Kdim; k0 += 16) {
        float4 av;
        const int grow = row0 + arow;
        if (grow < Mdim) {
            av = *(const float4*)(A + (size_t)grow * Kdim + k0 + ak4);
        } else {
            av = make_float4(0.f, 0.f, 0.f, 0.f);
        }
        As[ak4 + 0][arow] = av.x;
        As[ak4 + 1][arow] = av.y;
        As[ak4 + 2][arow] = av.z;
        As[ak4 + 3][arow] = av.w;

        const float4 bv = *(const float4*)(B + (size_t)(k0 + brow) * Ndim + col0 + bcol4);
        *(float4*)&Bs[brow][bcol4] = bv;

        __syncthreads();

        #pragma unroll
        for (int kk = 0; kk < 16; kk++) {
            const float4 a4 = *(const float4*)&As[kk][ty << 2];
            const float4 b4 = *(const float4*)&Bs[kk][tx << 2];
            const float aa[4] = {a4.x, a4.y, a4.z, a4.w};
            const float bb[4] = {b4.x, b4.y, b4.z, b4.w};
            #pragma unroll
            for (int i = 0; i < 4; i++)
                #pragma unroll
                for (int j = 0; j < 4; j++)
                    acc[i][j] += aa[i] * bb[j];
        }
        __syncthreads();
    }

    #pragma unroll
    for (int i = 0; i < 4; i++) {
        const int r = row0 + (ty << 2) + i;
        if (r < Mdim) {
            #pragma unroll
            for (int j = 0; j < 4; j++) {
                const int c = col0 + (tx << 2) + j;
                C[(size_t)r * Ndim + c] = acc[i][j] + bias[c];
            }
        }
    }
}

// ---------------------------------------------------------------------------
// Fused softmax + bilinear sampling, v2.
// One block = 4 queries (same n). Thread = (qi, m, c):
//   c  = tid & 7   -> channel quad (covers dv = c*4 .. c*4+3 via float4)
//   m  = (tid>>3) & 7
//   qi = tid >> 6  (0..3)
// Scalar math (softmax/pos/weights) redundant across only 8 lanes (was 32);
// v gathers are float4 (was scalar). Branchless border handling.
// ---------------------------------------------------------------------------
__global__ __launch_bounds__(256) void sample_kernel(
    const float* __restrict__ logits,   // (N*Q, 128)
    const float* __restrict__ off,      // (N*Q, 256) as (M,LK,2)
    const float* __restrict__ geom,     // (N*Q, 4)
    const float* __restrict__ v,        // (N*S, 256) as (s, m*32+dv)
    float* __restrict__ out)            // (N*Q, 256) out_mdv staging
{
    const int tid = threadIdx.x;
    const int c  = tid & 7;
    const int m  = (tid >> 3) & 7;
    const int qi = tid >> 6;
    const int n  = blockIdx.y;
    const int q0 = blockIdx.x << 2;     // 4 queries per block, QN % 4 == 0

    __shared__ float l_sm[4][128];
    __shared__ float o_sm[4][256];
    __shared__ float g_sm[4][4];

    const size_t qb0 = (size_t)n * QN + q0;

    // stage per-query small tensors (coalesced)
    {
        int i = tid;
        l_sm[i >> 7][i & 127] = logits[qb0 * 128 + i];
        i += 256;
        l_sm[i >> 7][i & 127] = logits[qb0 * 128 + i];
    }
    #pragma unroll
    for (int i = 0; i < 4; i++) {
        const int j = i * 256 + tid;
        o_sm[j >> 8][j & 255] = off[qb0 * 256 + j];
    }
    if (tid < 16) g_sm[tid >> 2][tid & 3] = geom[qb0 * 4 + tid];
    __syncthreads();

    // softmax over the 16 points of this (qi, m) — redundant across 8 c-lanes
    const float* lrow = &l_sm[qi][m * 16];
    float mx = -1e30f;
    #pragma unroll
    for (int lk = 0; lk < 16; lk++) mx = fmaxf(mx, lrow[lk]);
    float wexp[16];
    float ssum = 0.f;
    #pragma unroll
    for (int lk = 0; lk < 16; lk++) {
        wexp[lk] = __expf(lrow[lk] - mx);
        ssum += wexp[lk];
    }
    const float inv = 1.f / ssum;

    const float cx = g_sm[qi][0], cy = g_sm[qi][1];
    const float sx = g_sm[qi][2] * 0.125f, sy = g_sm[qi][3] * 0.125f;
    const float* orow = &o_sm[qi][m * 32];

    // base channel pointer: channels m*32 + c*4
    const float* vbase = v + (size_t)n * SN * 256 + (m * 32 + c * 4);

    float4 acc = make_float4(0.f, 0.f, 0.f, 0.f);

    #pragma unroll
    for (int lk = 0; lk < 16; lk++) {
        const int l = lk >> 2;
        const int Wl = 96 >> l;             // 96,48,24,12 (square levels)
        const int s0 = (l == 0) ? 0 : (l == 1) ? 9216 : (l == 2) ? 11520 : 12096;

        const float px = cx + orow[lk * 2 + 0] * sx;
        const float py = cy + orow[lk * 2 + 1] * sy;
        // grid = 2*pos-1; x = (grid+1)*(W/2)-0.5 == pos*W - 0.5
        const float x = px * (float)Wl - 0.5f;
        const float y = py * (float)Wl - 0.5f;
        const float xf = floorf(x), yf = floorf(y);
        const int x0 = (int)xf, y0 = (int)yf;
        const float wx = x - xf, wy = y - yf;

        const bool vx0 = (x0 >= 0) & (x0 < Wl);
        const bool vx1 = (x0 + 1 >= 0) & (x0 + 1 < Wl);
        const bool vy0 = (y0 >= 0) & (y0 < Wl);
        const bool vy1 = (y0 + 1 >= 0) & (y0 + 1 < Wl);

        const float wsc = wexp[lk] * inv;
        const float w00 = (vx0 & vy0) ? wsc * (1.f - wx) * (1.f - wy) : 0.f;
        const float w10 = (vx1 & vy0) ? wsc * wx * (1.f - wy) : 0.f;
        const float w01 = (vx0 & vy1) ? wsc * (1.f - wx) * wy : 0.f;
        const float w11 = (vx1 & vy1) ? wsc * wx * wy : 0.f;

        const int xc0 = min(max(x0, 0), Wl - 1);
        const int xc1 = min(max(x0 + 1, 0), Wl - 1);
        const int yc0 = min(max(y0, 0), Wl - 1);
        const int yc1 = min(max(y0 + 1, 0), Wl - 1);

        const float* vb = vbase + (size_t)s0 * 256;
        const float4 v00 = *(const float4*)(vb + (size_t)(yc0 * Wl + xc0) * 256);
        const float4 v10 = *(const float4*)(vb + (size_t)(yc0 * Wl + xc1) * 256);
        const float4 v01 = *(const float4*)(vb + (size_t)(yc1 * Wl + xc0) * 256);
        const float4 v11 = *(const float4*)(vb + (size_t)(yc1 * Wl + xc1) * 256);

        acc.x += w00 * v00.x + w10 * v10.x + w01 * v01.x + w11 * v11.x;
        acc.y += w00 * v00.y + w10 * v10.y + w01 * v01.y + w11 * v11.y;
        acc.z += w00 * v00.z + w10 * v10.z + w01 * v01.z + w11 * v11.z;
        acc.w += w00 * v00.w + w10 * v10.w + w01 * v01.w + w11 * v11.w;
    }

    *(float4*)(out + (qb0 + qi) * 256 + m * 32 + c * 4) = acc;
}

// ---------------------------------------------------------------------------
// Final GEMM, in-place on d_out: out[r,:] = out_mdv[r,:] @ W_out + b_out.
// Each block owns 16 rows exclusively (stages them in LDS before writing),
// so in-place is race-free. 256 threads; thread = output column d.
// ---------------------------------------------------------------------------
__global__ __launch_bounds__(256) void out_gemm_inplace(
    const float* __restrict__ Wout, const float* __restrict__ bout,
    float* __restrict__ out)
{
    __shared__ __align__(16) float A[16][256];
    const int d = threadIdx.x;
    const size_t row0 = (size_t)blockIdx.x * 16;

    #pragma unroll
    for (int r = 0; r < 16; r++) A[r][d] = out[(row0 + r) * 256 + d];
    __syncthreads();

    float acc[16];
    const float bb = bout[d];
    #pragma unroll
    for (int r = 0; r < 16; r++) acc[r] = bb;

    for (int k = 0; k < 256; k += 4) {
        const float w0 = Wout[(size_t)(k + 0) * 256 + d];
        const float w1 = Wout[(size_t)(k + 1) * 256 + d];
        const float w2 = Wout[(size_t)(k + 2) * 256 + d];
        const float w3 = Wout[(size_t)(k + 3) * 256 + d];
        #pragma unroll
        for (int r = 0; r < 16; r++) {
            const float4 a4 = *(const float4*)&A[r][k];
            acc[r] += a4.x * w0 + a4.y * w1 + a4.z * w2 + a4.w * w3;
        }
    }

    __syncthreads();
    #pragma unroll
    for (int r = 0; r < 16; r++) out[(row0 + r) * 256 + d] = acc[r];
}

// ---------------------------------------------------------------------------
extern "C" void kernel_launch(void* const* d_in, const int* in_sizes, int n_in,
                              void* d_out, int out_size, void* d_ws, size_t ws_size,
                              hipStream_t stream)
{
    const float* queries = (const float*)d_in[0];   // (N,Q,256)
    const float* geom    = (const float*)d_in[1];   // (N,Q,4)
    const float* src     = (const float*)d_in[2];   // (N,S,256)
    const float* W_off   = (const float*)d_in[3];   // (256,256)
    const float* b_off   = (const float*)d_in[4];   // (256,)
    const float* W_attn  = (const float*)d_in[5];   // (256,128)
    const float* b_attn  = (const float*)d_in[6];   // (128,)
    const float* W_val   = (const float*)d_in[7];   // (256,256)
    const float* b_val   = (const float*)d_in[8];   // (256,)
    const float* W_out   = (const float*)d_in[9];   // (256,256)
    const float* b_out   = (const float*)d_in[10];  // (256,)
    float* out = (float*)d_out;
    float* ws  = (float*)d_ws;

    const int ROWS = NB * QN;  // 24480
    float* v_ws      = ws;                      // 24480*256 floats
    float* logits_ws = ws + (size_t)6266880;    // 24480*128 floats
    float* off_ws    = ws + (size_t)9400320;    // 24480*256 floats
    // total ws use: 15,667,200 floats = 62.7 MB

    dim3 blk(256);
    const int gy = (ROWS + 63) / 64;  // 383

    // v = src @ W_val + b_val          (24480 x 256)
    gemm_bias_kernel<<<dim3(4, gy), blk, 0, stream>>>(src, W_val, b_val, v_ws, ROWS, 256, 256);
    // logits = q @ W_attn + b_attn     (24480 x 128)
    gemm_bias_kernel<<<dim3(2, gy), blk, 0, stream>>>(queries, W_attn, b_attn, logits_ws, ROWS, 128, 256);
    // off = q @ W_off + b_off          (24480 x 256)
    gemm_bias_kernel<<<dim3(4, gy), blk, 0, stream>>>(queries, W_off, b_off, off_ws, ROWS, 256, 256);
    // softmax + bilinear sample -> out_mdv (staged in d_out)
    sample_kernel<<<dim3(QN / 4, NB), blk, 0, stream>>>(logits_ws, off_ws, geom, v_ws, out);
    // out = out_mdv @ W_out + b_out (in-place on d_out)
    out_gemm_inplace<<<dim3(ROWS / 16), blk, 0, stream>>>(W_out, b_out, out);
}

// Round 3
// 234.714 us; speedup vs baseline: 2.4380x; 1.6808x over previous
//
#include <hip/hip_runtime.h>
#include <hip/hip_bf16.h>
#include <cstddef>

// Problem constants
#define NB 2
#define QN 12240
#define SN 12240
#define MH 8
#define MREAL 24480          // NB*QN rows
#define MPAD  24576          // 192 * 128
#define MT    192            // M tiles of 128

typedef unsigned short ushortT;
typedef unsigned int uintT;
typedef __bf16 bf16x8 __attribute__((ext_vector_type(8)));
typedef float f32x4 __attribute__((ext_vector_type(4)));

__device__ __forceinline__ ushortT f2bf(float f) {
    uintT u = __float_as_uint(f);
    uintT r = u + 0x7fffu + ((u >> 16) & 1u);   // RNE
    return (ushortT)(r >> 16);
}
__device__ __forceinline__ float bf2f(ushortT u) {
    return __uint_as_float((uintT)u << 16);
}

__device__ __forceinline__ void async_ld16(const ushortT* g, ushortT* l) {
    __builtin_amdgcn_global_load_lds(
        (const __attribute__((address_space(1))) unsigned int*)g,
        (__attribute__((address_space(3))) unsigned int*)l, 16, 0, 0);
}

// ---------------------------------------------------------------------------
// Cast queries + src (fp32, 24480x256) to bf16. blockIdx.y selects which.
// ---------------------------------------------------------------------------
__global__ __launch_bounds__(256) void cast_qsrc(
    const float* __restrict__ q, const float* __restrict__ src,
    ushortT* __restrict__ qb, ushortT* __restrict__ sb)
{
    const size_t idx = ((size_t)blockIdx.x * 256 + threadIdx.x) * 8;
    if (idx >= (size_t)MREAL * 256) return;
    const float* in = (blockIdx.y == 0) ? q : src;
    ushortT* out = (blockIdx.y == 0) ? qb : sb;
    const float4 a = *(const float4*)(in + idx);
    const float4 b = *(const float4*)(in + idx + 4);
    uint4 o;
    o.x = (uintT)f2bf(a.x) | ((uintT)f2bf(a.y) << 16);
    o.y = (uintT)f2bf(a.z) | ((uintT)f2bf(a.w) << 16);
    o.z = (uintT)f2bf(b.x) | ((uintT)f2bf(b.y) << 16);
    o.w = (uintT)f2bf(b.z) | ((uintT)f2bf(b.w) << 16);
    *(uint4*)(out + idx) = o;
}

// ---------------------------------------------------------------------------
// Cast + transpose all 4 weight matrices: Wt[n][k] = W[k][n] (bf16).
// Block ranges: [0,256) W_val, [256,384) W_attn(N=128), [384,640) W_off,
// [640,896) W_out. K=256 for all.
// ---------------------------------------------------------------------------
__global__ __launch_bounds__(256) void cast_weights(
    const float* __restrict__ Wval, const float* __restrict__ Wattn,
    const float* __restrict__ Woff, const float* __restrict__ Wout,
    ushortT* __restrict__ tval, ushortT* __restrict__ tattn,
    ushortT* __restrict__ toff, ushortT* __restrict__ tout)
{
    const int bx = blockIdx.x;
    const float* W; ushortT* T; int n, Nw;
    if (bx < 256)      { W = Wval;  T = tval;  n = bx;       Nw = 256; }
    else if (bx < 384) { W = Wattn; T = tattn; n = bx - 256; Nw = 128; }
    else if (bx < 640) { W = Woff;  T = toff;  n = bx - 384; Nw = 256; }
    else               { W = Wout;  T = tout;  n = bx - 640; Nw = 256; }
    const int k = threadIdx.x;   // K == 256
    T[(size_t)n * 256 + k] = f2bf(W[(size_t)k * Nw + n]);
}

// ---------------------------------------------------------------------------
// bf16 MFMA GEMM: C(Mreal,Ntot) = A(Mpad,K)bf16 @ Bt(Ntot,K)bf16^T + bias.
// 128x128 tile, BK=32, 256 threads (4 waves, 2x2 wave grid of 64x64).
// global_load_lds width-16 staging; ds_read_b128 frags; row-guarded epilogue.
// OBF: write bf16 C, else fp32 C.
// ---------------------------------------------------------------------------
template<bool OBF>
__global__ __launch_bounds__(256) void mfma_gemm(
    const ushortT* __restrict__ A, const ushortT* __restrict__ Bt,
    const float* __restrict__ bias, void* __restrict__ Cout,
    int Mreal, int Ntot, int K)
{
    __shared__ __attribute__((aligned(16))) ushortT As[128 * 32];
    __shared__ __attribute__((aligned(16))) ushortT Bs[128 * 32];

    const int tid  = threadIdx.x;
    const int wave = tid >> 6;
    const int lane = tid & 63;
    const int row0 = blockIdx.y * 128;
    const int col0 = blockIdx.x * 128;
    const int wr = (wave >> 1) * 64;
    const int wc = (wave & 1) * 64;

    f32x4 acc[4][4];
    #pragma unroll
    for (int i = 0; i < 4; i++)
        #pragma unroll
        for (int j = 0; j < 4; j++)
            acc[i][j] = (f32x4)0.f;

    // staging geometry: per call one wave covers 16 rows x 64B.
    const int srow = (lane >> 2);          // 0..15 row within 16-row chunk
    const int sk8  = (lane & 3) * 8;       // k offset in elems (16B quads)

    for (int k0 = 0; k0 < K; k0 += 32) {
        #pragma unroll
        for (int j = 0; j < 2; j++) {
            const int r = wave * 32 + j * 16;   // chunk base row (block-local)
            const ushortT* gA = A + (size_t)(row0 + r + srow) * K + k0 + sk8;
            async_ld16(gA, &As[r * 32]);
            const ushortT* gB = Bt + (size_t)(col0 + r + srow) * K + k0 + sk8;
            async_ld16(gB, &Bs[r * 32]);
        }
        __syncthreads();

        bf16x8 af[4], bfr[4];
        const int mrow = lane & 15;
        const int kq   = (lane >> 4) * 8;
        #pragma unroll
        for (int i = 0; i < 4; i++) {
            af[i]  = *(const bf16x8*)&As[(wr + i * 16 + mrow) * 32 + kq];
            bfr[i] = *(const bf16x8*)&Bs[(wc + i * 16 + mrow) * 32 + kq];
        }
        #pragma unroll
        for (int i = 0; i < 4; i++)
            #pragma unroll
            for (int j = 0; j < 4; j++)
                acc[i][j] = __builtin_amdgcn_mfma_f32_16x16x32_bf16(
                    af[i], bfr[j], acc[i][j], 0, 0, 0);
        __syncthreads();
    }

    // epilogue: row = (lane>>4)*4 + reg, col = lane&15  (per 16x16 frag)
    #pragma unroll
    for (int i = 0; i < 4; i++) {
        const int rbase = row0 + wr + i * 16 + ((lane >> 4) << 2);
        #pragma unroll
        for (int j = 0; j < 4; j++) {
            const int col = col0 + wc + j * 16 + (lane & 15);
            const float bb = bias[col];
            #pragma unroll
            for (int r = 0; r < 4; r++) {
                const int row = rbase + r;
                if (row < Mreal) {
                    const float val = acc[i][j][r] + bb;
                    if (OBF) ((ushortT*)Cout)[(size_t)row * Ntot + col] = f2bf(val);
                    else     ((float*)Cout)[(size_t)row * Ntot + col] = val;
                }
            }
        }
    }
}

// ---------------------------------------------------------------------------
// Fused softmax + bilinear sampling (v from bf16, out_mdv to bf16).
// One block = 4 queries. Thread = (qi, m, c): c covers 4 channels.
// ---------------------------------------------------------------------------
__global__ __launch_bounds__(256) void sample_kernel(
    const float* __restrict__ logits,     // (N*Q, 128)
    const float* __restrict__ off,        // (N*Q, 256)
    const float* __restrict__ geom,       // (N*Q, 4)
    const ushortT* __restrict__ v,        // (N*S, 256) bf16
    ushortT* __restrict__ out)            // (N*Q, 256) bf16 out_mdv
{
    const int tid = threadIdx.x;
    const int c  = tid & 7;
    const int m  = (tid >> 3) & 7;
    const int qi = tid >> 6;
    const int n  = blockIdx.y;
    const int q0 = blockIdx.x << 2;

    __shared__ float l_sm[4][128];
    __shared__ float o_sm[4][256];
    __shared__ float g_sm[4][4];

    const size_t qb0 = (size_t)n * QN + q0;

    {
        int i = tid;
        l_sm[i >> 7][i & 127] = logits[qb0 * 128 + i];
        i += 256;
        l_sm[i >> 7][i & 127] = logits[qb0 * 128 + i];
    }
    #pragma unroll
    for (int i = 0; i < 4; i++) {
        const int j = i * 256 + tid;
        o_sm[j >> 8][j & 255] = off[qb0 * 256 + j];
    }
    if (tid < 16) g_sm[tid >> 2][tid & 3] = geom[qb0 * 4 + tid];
    __syncthreads();

    const float* lrow = &l_sm[qi][m * 16];
    float mx = -1e30f;
    #pragma unroll
    for (int lk = 0; lk < 16; lk++) mx = fmaxf(mx, lrow[lk]);
    float wexp[16];
    float ssum = 0.f;
    #pragma unroll
    for (int lk = 0; lk < 16; lk++) {
        wexp[lk] = __expf(lrow[lk] - mx);
        ssum += wexp[lk];
    }
    const float inv = 1.f / ssum;

    const float cx = g_sm[qi][0], cy = g_sm[qi][1];
    const float sx = g_sm[qi][2] * 0.125f, sy = g_sm[qi][3] * 0.125f;
    const float* orow = &o_sm[qi][m * 32];

    const ushortT* vbase = v + (size_t)n * SN * 256 + (m * 32 + c * 4);

    float4 acc = make_float4(0.f, 0.f, 0.f, 0.f);

    #pragma unroll
    for (int lk = 0; lk < 16; lk++) {
        const int l = lk >> 2;
        const int Wl = 96 >> l;
        const int s0 = (l == 0) ? 0 : (l == 1) ? 9216 : (l == 2) ? 11520 : 12096;

        const float px = cx + orow[lk * 2 + 0] * sx;
        const float py = cy + orow[lk * 2 + 1] * sy;
        const float x = px * (float)Wl - 0.5f;
        const float y = py * (float)Wl - 0.5f;
        const float xf = floorf(x), yf = floorf(y);
        const int x0 = (int)xf, y0 = (int)yf;
        const float wx = x - xf, wy = y - yf;

        const bool vx0 = (x0 >= 0) & (x0 < Wl);
        const bool vx1 = (x0 + 1 >= 0) & (x0 + 1 < Wl);
        const bool vy0 = (y0 >= 0) & (y0 < Wl);
        const bool vy1 = (y0 + 1 >= 0) & (y0 + 1 < Wl);

        const float wsc = wexp[lk] * inv;
        const float w00 = (vx0 & vy0) ? wsc * (1.f - wx) * (1.f - wy) : 0.f;
        const float w10 = (vx1 & vy0) ? wsc * wx * (1.f - wy) : 0.f;
        const float w01 = (vx0 & vy1) ? wsc * (1.f - wx) * wy : 0.f;
        const float w11 = (vx1 & vy1) ? wsc * wx * wy : 0.f;

        const int xc0 = min(max(x0, 0), Wl - 1);
        const int xc1 = min(max(x0 + 1, 0), Wl - 1);
        const int yc0 = min(max(y0, 0), Wl - 1);
        const int yc1 = min(max(y0 + 1, 0), Wl - 1);

        const ushortT* vb = vbase + (size_t)s0 * 256;
        const ushort4 u00 = *(const ushort4*)(vb + (size_t)(yc0 * Wl + xc0) * 256);
        const ushort4 u10 = *(const ushort4*)(vb + (size_t)(yc0 * Wl + xc1) * 256);
        const ushort4 u01 = *(const ushort4*)(vb + (size_t)(yc1 * Wl + xc0) * 256);
        const ushort4 u11 = *(const ushort4*)(vb + (size_t)(yc1 * Wl + xc1) * 256);

        acc.x += w00 * bf2f(u00.x) + w10 * bf2f(u10.x) + w01 * bf2f(u01.x) + w11 * bf2f(u11.x);
        acc.y += w00 * bf2f(u00.y) + w10 * bf2f(u10.y) + w01 * bf2f(u01.y) + w11 * bf2f(u11.y);
        acc.z += w00 * bf2f(u00.z) + w10 * bf2f(u10.z) + w01 * bf2f(u01.z) + w11 * bf2f(u11.z);
        acc.w += w00 * bf2f(u00.w) + w10 * bf2f(u10.w) + w01 * bf2f(u01.w) + w11 * bf2f(u11.w);
    }

    ushort4 o;
    o.x = f2bf(acc.x); o.y = f2bf(acc.y); o.z = f2bf(acc.z); o.w = f2bf(acc.w);
    *(ushort4*)(out + (qb0 + qi) * 256 + m * 32 + c * 4) = o;
}

// ---------------------------------------------------------------------------
extern "C" void kernel_launch(void* const* d_in, const int* in_sizes, int n_in,
                              void* d_out, int out_size, void* d_ws, size_t ws_size,
                              hipStream_t stream)
{
    const float* queries = (const float*)d_in[0];
    const float* geom    = (const float*)d_in[1];
    const float* src     = (const float*)d_in[2];
    const float* W_off   = (const float*)d_in[3];
    const float* b_off   = (const float*)d_in[4];
    const float* W_attn  = (const float*)d_in[5];
    const float* b_attn  = (const float*)d_in[6];
    const float* W_val   = (const float*)d_in[7];
    const float* b_val   = (const float*)d_in[8];
    const float* W_out   = (const float*)d_in[9];
    const float* b_out   = (const float*)d_in[10];
    float* out = (float*)d_out;

    // workspace layout (bf16 region then fp32 region)
    ushortT* wsb = (ushortT*)d_ws;
    const size_t PADROW = (size_t)MPAD * 256;          // 6,291,456 elems
    ushortT* q_bf    = wsb;                            // padded reserve
    ushortT* srcmdv  = wsb + PADROW;                   // src_bf, later mdv_bf
    ushortT* v_bf    = wsb + 2 * PADROW;               // padded reserve
    ushortT* wt_val  = wsb + 3 * PADROW;               // 256*256
    ushortT* wt_attn = wt_val + 65536;                 // 128*256
    ushortT* wt_off  = wt_attn + 32768;                // 256*256
    ushortT* wt_out  = wt_off + 65536;                 // 256*256
    float* fp = (float*)(wt_out + 65536);
    float* logits_ws = fp;                             // 24480*128
    float* off_ws    = fp + (size_t)MREAL * 128;       // 24480*256 (last)
    // total ~75.8 MB

    dim3 blk(256);

    // casts
    cast_qsrc<<<dim3((MREAL * 256 / 8 + 255) / 256, 2), blk, 0, stream>>>(
        queries, src, q_bf, srcmdv);
    cast_weights<<<dim3(896), blk, 0, stream>>>(
        W_val, W_attn, W_off, W_out, wt_val, wt_attn, wt_off, wt_out);

    // v = src @ W_val + b_val -> bf16
    mfma_gemm<true><<<dim3(2, MT), blk, 0, stream>>>(
        srcmdv, wt_val, b_val, v_bf, MREAL, 256, 256);
    // logits = q @ W_attn + b_attn -> fp32
    mfma_gemm<false><<<dim3(1, MT), blk, 0, stream>>>(
        q_bf, wt_attn, b_attn, logits_ws, MREAL, 128, 256);
    // off = q @ W_off + b_off -> fp32
    mfma_gemm<false><<<dim3(2, MT), blk, 0, stream>>>(
        q_bf, wt_off, b_off, off_ws, MREAL, 256, 256);

    // softmax + bilinear sample -> mdv (bf16, reuses src_bf buffer)
    sample_kernel<<<dim3(QN / 4, NB), blk, 0, stream>>>(
        logits_ws, off_ws, geom, v_bf, srcmdv);

    // out = mdv @ W_out + b_out -> d_out fp32
    mfma_gemm<false><<<dim3(2, MT), blk, 0, stream>>>(
        srcmdv, wt_out, b_out, out, MREAL, 256, 256);
}

// Round 4
// 214.418 us; speedup vs baseline: 2.6688x; 1.0947x over previous
//
#include <hip/hip_runtime.h>
#include <hip/hip_bf16.h>
#include <cstddef>

// Problem constants
#define NB 2
#define QN 12240
#define SN 12240
#define MREAL 24480          // NB*QN rows
#define MPAD  24576          // 192 * 128
#define MT    192            // M tiles of 128

typedef unsigned short ushortT;
typedef unsigned int uintT;
typedef __bf16 bf16x8 __attribute__((ext_vector_type(8)));
typedef float f32x4 __attribute__((ext_vector_type(4)));

__device__ __forceinline__ ushortT f2bf(float f) {
    uintT u = __float_as_uint(f);
    uintT r = u + 0x7fffu + ((u >> 16) & 1u);   // RNE
    return (ushortT)(r >> 16);
}
__device__ __forceinline__ float bf2f(ushortT u) {
    return __uint_as_float((uintT)u << 16);
}

__device__ __forceinline__ void async_ld16(const ushortT* g, ushortT* l) {
    __builtin_amdgcn_global_load_lds(
        (const __attribute__((address_space(1))) unsigned int*)g,
        (__attribute__((address_space(3))) unsigned int*)l, 16, 0, 0);
}

// ---------------------------------------------------------------------------
// Cast queries + src (fp32, 24480x256) to bf16. blockIdx.y selects which.
// ---------------------------------------------------------------------------
__global__ __launch_bounds__(256) void cast_qsrc(
    const float* __restrict__ q, const float* __restrict__ src,
    ushortT* __restrict__ qb, ushortT* __restrict__ sb)
{
    const size_t idx = ((size_t)blockIdx.x * 256 + threadIdx.x) * 8;
    if (idx >= (size_t)MREAL * 256) return;
    const float* in = (blockIdx.y == 0) ? q : src;
    ushortT* out = (blockIdx.y == 0) ? qb : sb;
    const float4 a = *(const float4*)(in + idx);
    const float4 b = *(const float4*)(in + idx + 4);
    uint4 o;
    o.x = (uintT)f2bf(a.x) | ((uintT)f2bf(a.y) << 16);
    o.y = (uintT)f2bf(a.z) | ((uintT)f2bf(a.w) << 16);
    o.z = (uintT)f2bf(b.x) | ((uintT)f2bf(b.y) << 16);
    o.w = (uintT)f2bf(b.z) | ((uintT)f2bf(b.w) << 16);
    *(uint4*)(out + idx) = o;
}

// ---------------------------------------------------------------------------
// Cast + transpose weights: Wt[n][k] = W[k][n] (bf16).
// [0,256) W_val -> tval; [256,384) W_attn -> tlo rows 0..127;
// [384,640) W_off -> tlo rows 128..383; [640,896) W_out -> tout.
// ---------------------------------------------------------------------------
__global__ __launch_bounds__(256) void cast_weights(
    const float* __restrict__ Wval, const float* __restrict__ Wattn,
    const float* __restrict__ Woff, const float* __restrict__ Wout,
    ushortT* __restrict__ tval, ushortT* __restrict__ tlo,
    ushortT* __restrict__ tout)
{
    const int bx = blockIdx.x;
    const float* W; ushortT* T; int n, Nw, trow;
    if (bx < 256)      { W = Wval;  T = tval; n = bx;       Nw = 256; trow = n; }
    else if (bx < 384) { W = Wattn; T = tlo;  n = bx - 256; Nw = 128; trow = n; }
    else if (bx < 640) { W = Woff;  T = tlo;  n = bx - 384; Nw = 256; trow = n + 128; }
    else               { W = Wout;  T = tout; n = bx - 640; Nw = 256; trow = n; }
    const int k = threadIdx.x;   // K == 256
    T[(size_t)trow * 256 + k] = f2bf(W[(size_t)k * Nw + n]);
}

// ---------------------------------------------------------------------------
// Fused v + (logits|off) GEMM. z=0: v = src@W_val (Ntot=256, bf16 out).
// z=1: lo = q@[W_attn;W_off] (Ntot=384, fp32 out, per-column-tile bias).
// 128x128 tile, BK=32, K=256, 256 threads.
// ---------------------------------------------------------------------------
__global__ __launch_bounds__(256) void gemm_vlo(
    const ushortT* __restrict__ q_bf, const ushortT* __restrict__ src_bf,
    const ushortT* __restrict__ wt_val, const ushortT* __restrict__ wt_lo,
    const float* __restrict__ b_val, const float* __restrict__ b_attn,
    const float* __restrict__ b_off,
    ushortT* __restrict__ v_bf, float* __restrict__ lo_ws)
{
    const int z = blockIdx.z;
    if (z == 0 && blockIdx.x >= 2) return;

    __shared__ __attribute__((aligned(16))) ushortT As[128 * 32];
    __shared__ __attribute__((aligned(16))) ushortT Bs[128 * 32];

    const ushortT* A  = z ? q_bf : src_bf;
    const ushortT* Bt = z ? wt_lo : wt_val;

    const int tid  = threadIdx.x;
    const int wave = tid >> 6;
    const int lane = tid & 63;
    const int row0 = blockIdx.y * 128;
    const int col0 = blockIdx.x * 128;
    const int wr = (wave >> 1) * 64;
    const int wc = (wave & 1) * 64;

    f32x4 acc[4][4];
    #pragma unroll
    for (int i = 0; i < 4; i++)
        #pragma unroll
        for (int j = 0; j < 4; j++)
            acc[i][j] = (f32x4)0.f;

    const int srow = (lane >> 2);
    const int sk8  = (lane & 3) * 8;

    for (int k0 = 0; k0 < 256; k0 += 32) {
        #pragma unroll
        for (int j = 0; j < 2; j++) {
            const int r = wave * 32 + j * 16;
            async_ld16(A  + (size_t)(row0 + r + srow) * 256 + k0 + sk8, &As[r * 32]);
            async_ld16(Bt + (size_t)(col0 + r + srow) * 256 + k0 + sk8, &Bs[r * 32]);
        }
        __syncthreads();

        bf16x8 af[4], bfr[4];
        const int mrow = lane & 15;
        const int kq   = (lane >> 4) * 8;
        #pragma unroll
        for (int i = 0; i < 4; i++) {
            af[i]  = *(const bf16x8*)&As[(wr + i * 16 + mrow) * 32 + kq];
            bfr[i] = *(const bf16x8*)&Bs[(wc + i * 16 + mrow) * 32 + kq];
        }
        #pragma unroll
        for (int i = 0; i < 4; i++)
            #pragma unroll
            for (int j = 0; j < 4; j++)
                acc[i][j] = __builtin_amdgcn_mfma_f32_16x16x32_bf16(
                    af[i], bfr[j], acc[i][j], 0, 0, 0);
        __syncthreads();
    }

    const int Ntot = z ? 384 : 256;
    const float* bp = z ? ((col0 < 128) ? b_attn : b_off) : b_val;
    const int cofs  = (z && col0 >= 128) ? 128 : 0;

    #pragma unroll
    for (int i = 0; i < 4; i++) {
        const int rbase = row0 + wr + i * 16 + ((lane >> 4) << 2);
        #pragma unroll
        for (int j = 0; j < 4; j++) {
            const int col = col0 + wc + j * 16 + (lane & 15);
            const float bb = bp[col - cofs];
            #pragma unroll
            for (int r = 0; r < 4; r++) {
                const int row = rbase + r;
                if (row < MREAL) {
                    const float val = acc[i][j][r] + bb;
                    if (z) lo_ws[(size_t)row * 384 + col] = val;
                    else   v_bf[(size_t)row * 256 + col] = f2bf(val);
                }
            }
        }
    }
}

// ---------------------------------------------------------------------------
// Out GEMM: out(MREAL,256) = mdv(bf16) @ wt_out^T + b_out (fp32 to d_out).
// ---------------------------------------------------------------------------
__global__ __launch_bounds__(256) void gemm_out(
    const ushortT* __restrict__ A, const ushortT* __restrict__ Bt,
    const float* __restrict__ bias, float* __restrict__ C)
{
    __shared__ __attribute__((aligned(16))) ushortT As[128 * 32];
    __shared__ __attribute__((aligned(16))) ushortT Bs[128 * 32];

    const int tid  = threadIdx.x;
    const int wave = tid >> 6;
    const int lane = tid & 63;
    const int row0 = blockIdx.y * 128;
    const int col0 = blockIdx.x * 128;
    const int wr = (wave >> 1) * 64;
    const int wc = (wave & 1) * 64;

    f32x4 acc[4][4];
    #pragma unroll
    for (int i = 0; i < 4; i++)
        #pragma unroll
        for (int j = 0; j < 4; j++)
            acc[i][j] = (f32x4)0.f;

    const int srow = (lane >> 2);
    const int sk8  = (lane & 3) * 8;

    for (int k0 = 0; k0 < 256; k0 += 32) {
        #pragma unroll
        for (int j = 0; j < 2; j++) {
            const int r = wave * 32 + j * 16;
            async_ld16(A  + (size_t)(row0 + r + srow) * 256 + k0 + sk8, &As[r * 32]);
            async_ld16(Bt + (size_t)(col0 + r + srow) * 256 + k0 + sk8, &Bs[r * 32]);
        }
        __syncthreads();

        bf16x8 af[4], bfr[4];
        const int mrow = lane & 15;
        const int kq   = (lane >> 4) * 8;
        #pragma unroll
        for (int i = 0; i < 4; i++) {
            af[i]  = *(const bf16x8*)&As[(wr + i * 16 + mrow) * 32 + kq];
            bfr[i] = *(const bf16x8*)&Bs[(wc + i * 16 + mrow) * 32 + kq];
        }
        #pragma unroll
        for (int i = 0; i < 4; i++)
            #pragma unroll
            for (int j = 0; j < 4; j++)
                acc[i][j] = __builtin_amdgcn_mfma_f32_16x16x32_bf16(
                    af[i], bfr[j], acc[i][j], 0, 0, 0);
        __syncthreads();
    }

    #pragma unroll
    for (int i = 0; i < 4; i++) {
        const int rbase = row0 + wr + i * 16 + ((lane >> 4) << 2);
        #pragma unroll
        for (int j = 0; j < 4; j++) {
            const int col = col0 + wc + j * 16 + (lane & 15);
            const float bb = bias[col];
            #pragma unroll
            for (int r = 0; r < 4; r++) {
                const int row = rbase + r;
                if (row < MREAL)
                    C[(size_t)row * 256 + col] = acc[i][j][r] + bb;
            }
        }
    }
}

// ---------------------------------------------------------------------------
// Two-phase sample kernel. Block = 4 queries (one n).
// Phase 1: thread=(qi,m,p): softmax via shfl, bilinear weights (pre-scaled
//   by attn) + corner byte-offsets for 2 points -> LDS (132-dword stride).
// Phase 2: thread=(qi,m,c): per point 2x ds_read_b128 (conflict-free
//   broadcast), 4 gathers, 16 cvt+fma.
// ---------------------------------------------------------------------------
__global__ __launch_bounds__(256) void sample_kernel(
    const float* __restrict__ lo,       // (N*Q, 384): [0,128) logits, [128,384) off
    const float* __restrict__ geom,     // (N*Q, 4)
    const ushortT* __restrict__ v,      // (N*S, 256) bf16
    ushortT* __restrict__ out)          // (N*Q, 256) bf16 mdv
{
    const int tid = threadIdx.x;
    const int n  = blockIdx.y;
    const int q0 = blockIdx.x << 2;
    const int qi = tid >> 6;
    const int m  = (tid >> 3) & 7;

    __shared__ __attribute__((aligned(16))) int pls[32 * 132];  // 16.9 KB

    // ---- phase 1 ----
    {
        const int p = tid & 7;                       // point pair 0..7
        const size_t qb = (size_t)n * QN + q0 + qi;
        const float* lorow = lo + qb * 384;
        const float2 lg = *(const float2*)(lorow + m * 16 + p * 2);
        const float4 of = *(const float4*)(lorow + 128 + m * 32 + p * 4);
        const float4 g  = *(const float4*)(geom + qb * 4);

        float mx = fmaxf(lg.x, lg.y);
        mx = fmaxf(mx, __shfl_xor(mx, 1));
        mx = fmaxf(mx, __shfl_xor(mx, 2));
        mx = fmaxf(mx, __shfl_xor(mx, 4));
        const float e0 = __expf(lg.x - mx);
        const float e1 = __expf(lg.y - mx);
        float s = e0 + e1;
        s += __shfl_xor(s, 1);
        s += __shfl_xor(s, 2);
        s += __shfl_xor(s, 4);
        const float inv = 1.f / s;

        const int l  = p >> 1;
        const int Wl = 96 >> l;
        const int s0 = (l == 0) ? 0 : (l == 1) ? 9216 : (l == 2) ? 11520 : 12096;
        const float cx = g.x, cy = g.y;
        const float sx = g.z * 0.125f, sy = g.w * 0.125f;
        const int base = (qi * 8 + m) * 132 + p * 16;

        #pragma unroll
        for (int t = 0; t < 2; t++) {
            const float ox = t ? of.z : of.x;
            const float oy = t ? of.w : of.y;
            const float wa = (t ? e1 : e0) * inv;

            const float x = (cx + ox * sx) * (float)Wl - 0.5f;
            const float y = (cy + oy * sy) * (float)Wl - 0.5f;
            const float xf = floorf(x), yf = floorf(y);
            const int x0 = (int)xf, y0 = (int)yf;
            const float wx = x - xf, wy = y - yf;

            const bool vx0 = (x0 >= 0) & (x0 < Wl);
            const bool vx1 = (x0 + 1 >= 0) & (x0 + 1 < Wl);
            const bool vy0 = (y0 >= 0) & (y0 < Wl);
            const bool vy1 = (y0 + 1 >= 0) & (y0 + 1 < Wl);

            float4 wv;
            wv.x = (vx0 & vy0) ? wa * (1.f - wx) * (1.f - wy) : 0.f;
            wv.y = (vx1 & vy0) ? wa * wx * (1.f - wy) : 0.f;
            wv.z = (vx0 & vy1) ? wa * (1.f - wx) * wy : 0.f;
            wv.w = (vx1 & vy1) ? wa * wx * wy : 0.f;

            const int xc0 = min(max(x0, 0), Wl - 1);
            const int xc1 = min(max(x0 + 1, 0), Wl - 1);
            const int yc0 = min(max(y0, 0), Wl - 1);
            const int yc1 = min(max(y0 + 1, 0), Wl - 1);

            int4 iv;  // byte offsets into v (row stride 512 B)
            iv.x = (s0 + yc0 * Wl + xc0) << 9;
            iv.y = (s0 + yc0 * Wl + xc1) << 9;
            iv.z = (s0 + yc1 * Wl + xc0) << 9;
            iv.w = (s0 + yc1 * Wl + xc1) << 9;

            *(int4*)&pls[base + t * 8]       = iv;
            *(float4*)&pls[base + t * 8 + 4] = wv;
        }
    }
    __syncthreads();

    // ---- phase 2 ----
    const int c = tid & 7;
    const int chan_byte = (m * 32 + c * 4) * 2;
    const unsigned char* vb = (const unsigned char*)(v + (size_t)n * SN * 256);
    const int gbase = (qi * 8 + m) * 132;

    float4 acc = make_float4(0.f, 0.f, 0.f, 0.f);

    #pragma unroll
    for (int lk = 0; lk < 16; lk++) {
        const int4   iv = *(const int4*)&pls[gbase + lk * 8];
        const float4 w  = *(const float4*)&pls[gbase + lk * 8 + 4];

        const ushort4 u00 = *(const ushort4*)(vb + (size_t)(iv.x + chan_byte));
        const ushort4 u10 = *(const ushort4*)(vb + (size_t)(iv.y + chan_byte));
        const ushort4 u01 = *(const ushort4*)(vb + (size_t)(iv.z + chan_byte));
        const ushort4 u11 = *(const ushort4*)(vb + (size_t)(iv.w + chan_byte));

        acc.x += w.x * bf2f(u00.x) + w.y * bf2f(u10.x) + w.z * bf2f(u01.x) + w.w * bf2f(u11.x);
        acc.y += w.x * bf2f(u00.y) + w.y * bf2f(u10.y) + w.z * bf2f(u01.y) + w.w * bf2f(u11.y);
        acc.z += w.x * bf2f(u00.z) + w.y * bf2f(u10.z) + w.z * bf2f(u01.z) + w.w * bf2f(u11.z);
        acc.w += w.x * bf2f(u00.w) + w.y * bf2f(u10.w) + w.z * bf2f(u01.w) + w.w * bf2f(u11.w);
    }

    ushort4 o;
    o.x = f2bf(acc.x); o.y = f2bf(acc.y); o.z = f2bf(acc.z); o.w = f2bf(acc.w);
    const size_t qb = (size_t)n * QN + q0 + qi;
    *(ushort4*)(out + qb * 256 + m * 32 + c * 4) = o;
}

// ---------------------------------------------------------------------------
extern "C" void kernel_launch(void* const* d_in, const int* in_sizes, int n_in,
                              void* d_out, int out_size, void* d_ws, size_t ws_size,
                              hipStream_t stream)
{
    const float* queries = (const float*)d_in[0];
    const float* geom    = (const float*)d_in[1];
    const float* src     = (const float*)d_in[2];
    const float* b_off   = (const float*)d_in[4];
    const float* W_off   = (const float*)d_in[3];
    const float* W_attn  = (const float*)d_in[5];
    const float* b_attn  = (const float*)d_in[6];
    const float* W_val   = (const float*)d_in[7];
    const float* b_val   = (const float*)d_in[8];
    const float* W_out   = (const float*)d_in[9];
    const float* b_out   = (const float*)d_in[10];
    float* out = (float*)d_out;

    ushortT* wsb = (ushortT*)d_ws;
    const size_t PADROW = (size_t)MPAD * 256;          // 6,291,456 elems
    ushortT* q_bf    = wsb;
    ushortT* srcmdv  = wsb + PADROW;                   // src_bf, later mdv_bf
    ushortT* v_bf    = wsb + 2 * PADROW;
    ushortT* wt_val  = wsb + 3 * PADROW;               // 256*256
    ushortT* wt_lo   = wt_val + 65536;                 // 384*256
    ushortT* wt_out  = wt_lo + 98304;                  // 256*256
    float* lo_ws = (float*)(wt_out + 65536);           // 24480*384 fp32
    // total ~75.8 MB

    dim3 blk(256);

    cast_qsrc<<<dim3(3060, 2), blk, 0, stream>>>(queries, src, q_bf, srcmdv);
    cast_weights<<<dim3(896), blk, 0, stream>>>(
        W_val, W_attn, W_off, W_out, wt_val, wt_lo, wt_out);

    // z=0: v = src@W_val -> v_bf (bf16); z=1: lo = q@[W_attn;W_off] -> lo_ws
    gemm_vlo<<<dim3(3, MT, 2), blk, 0, stream>>>(
        q_bf, srcmdv, wt_val, wt_lo, b_val, b_attn, b_off, v_bf, lo_ws);

    sample_kernel<<<dim3(QN / 4, NB), blk, 0, stream>>>(
        lo_ws, geom, v_bf, srcmdv);

    gemm_out<<<dim3(2, MT), blk, 0, stream>>>(srcmdv, wt_out, b_out, out);
}

// Round 5
// 208.022 us; speedup vs baseline: 2.7509x; 1.0307x over previous
//
#include <hip/hip_runtime.h>
#include <hip/hip_bf16.h>
#include <hip/hip_fp16.h>
#include <cstddef>

// Problem constants
#define NB 2
#define QN 12240
#define SN 12240
#define MREAL 24480          // NB*QN rows
#define MPAD  24576          // 192 * 128
#define MT    192            // M tiles of 128

typedef unsigned short ushortT;
typedef unsigned int uintT;
typedef __bf16 bf16x8 __attribute__((ext_vector_type(8)));
typedef float f32x4 __attribute__((ext_vector_type(4)));

__device__ __forceinline__ ushortT f2bf(float f) {
    uintT u = __float_as_uint(f);
    uintT r = u + 0x7fffu + ((u >> 16) & 1u);   // RNE
    return (ushortT)(r >> 16);
}
__device__ __forceinline__ float bf_lo(uintT u) {   // low bf16 -> f32
    return __uint_as_float(u << 16);
}
__device__ __forceinline__ float bf_hi(uintT u) {   // high bf16 -> f32
    return __uint_as_float(u & 0xffff0000u);
}

__device__ __forceinline__ void async_ld16(const ushortT* g, ushortT* l) {
    __builtin_amdgcn_global_load_lds(
        (const __attribute__((address_space(1))) unsigned int*)g,
        (__attribute__((address_space(3))) unsigned int*)l, 16, 0, 0);
}

// ---------------------------------------------------------------------------
// Merged cast kernel.
// bx in [0,3060): queries -> q_bf (bf16)
// bx in [3060,6120): src -> src_bf
// bx in [6120,7016): weight cast+transpose (W_val/W_attn/W_off/W_out)
// ---------------------------------------------------------------------------
__global__ __launch_bounds__(256) void cast_all(
    const float* __restrict__ q, const float* __restrict__ src,
    const float* __restrict__ Wval, const float* __restrict__ Wattn,
    const float* __restrict__ Woff, const float* __restrict__ Wout,
    ushortT* __restrict__ qb, ushortT* __restrict__ sb,
    ushortT* __restrict__ tval, ushortT* __restrict__ tlo,
    ushortT* __restrict__ tout)
{
    int bx = blockIdx.x;
    if (bx < 6120) {
        const int issrc = bx >= 3060;
        const size_t idx = ((size_t)(bx - (issrc ? 3060 : 0)) * 256 + threadIdx.x) * 8;
        const float* in = issrc ? src : q;
        ushortT* out = issrc ? sb : qb;
        const float4 a = *(const float4*)(in + idx);
        const float4 b = *(const float4*)(in + idx + 4);
        uint4 o;
        o.x = (uintT)f2bf(a.x) | ((uintT)f2bf(a.y) << 16);
        o.y = (uintT)f2bf(a.z) | ((uintT)f2bf(a.w) << 16);
        o.z = (uintT)f2bf(b.x) | ((uintT)f2bf(b.y) << 16);
        o.w = (uintT)f2bf(b.z) | ((uintT)f2bf(b.w) << 16);
        *(uint4*)(out + idx) = o;
        return;
    }
    bx -= 6120;
    const float* W; ushortT* T; int n, Nw, trow;
    if (bx < 256)      { W = Wval;  T = tval; n = bx;       Nw = 256; trow = n; }
    else if (bx < 384) { W = Wattn; T = tlo;  n = bx - 256; Nw = 128; trow = n; }
    else if (bx < 640) { W = Woff;  T = tlo;  n = bx - 384; Nw = 256; trow = n + 128; }
    else               { W = Wout;  T = tout; n = bx - 640; Nw = 256; trow = n; }
    const int k = threadIdx.x;
    T[(size_t)trow * 256 + k] = f2bf(W[(size_t)k * Nw + n]);
}

// ---------------------------------------------------------------------------
// Fused v + (logits|off) GEMM, flat grid (5 x-blocks, no dead blocks).
// bx<2: v = src@W_val (col0=bx*128, bf16 out, Ntot=256)
// bx>=2: lo = q@[W_attn;W_off] (col0=(bx-2)*128, fp32 out, Ntot=384)
// ---------------------------------------------------------------------------
__global__ __launch_bounds__(256) void gemm_vlo(
    const ushortT* __restrict__ q_bf, const ushortT* __restrict__ src_bf,
    const ushortT* __restrict__ wt_val, const ushortT* __restrict__ wt_lo,
    const float* __restrict__ b_val, const float* __restrict__ b_attn,
    const float* __restrict__ b_off,
    ushortT* __restrict__ v_bf, float* __restrict__ lo_ws)
{
    const int z = blockIdx.x >= 2;
    const int col0 = (z ? blockIdx.x - 2 : blockIdx.x) * 128;

    __shared__ __attribute__((aligned(16))) ushortT As[128 * 32];
    __shared__ __attribute__((aligned(16))) ushortT Bs[128 * 32];

    const ushortT* A  = z ? q_bf : src_bf;
    const ushortT* Bt = z ? wt_lo : wt_val;

    const int tid  = threadIdx.x;
    const int wave = tid >> 6;
    const int lane = tid & 63;
    const int row0 = blockIdx.y * 128;
    const int wr = (wave >> 1) * 64;
    const int wc = (wave & 1) * 64;

    f32x4 acc[4][4];
    #pragma unroll
    for (int i = 0; i < 4; i++)
        #pragma unroll
        for (int j = 0; j < 4; j++)
            acc[i][j] = (f32x4)0.f;

    const int srow = (lane >> 2);
    const int sk8  = (lane & 3) * 8;

    for (int k0 = 0; k0 < 256; k0 += 32) {
        #pragma unroll
        for (int j = 0; j < 2; j++) {
            const int r = wave * 32 + j * 16;
            async_ld16(A  + (size_t)(row0 + r + srow) * 256 + k0 + sk8, &As[r * 32]);
            async_ld16(Bt + (size_t)(col0 + r + srow) * 256 + k0 + sk8, &Bs[r * 32]);
        }
        __syncthreads();

        bf16x8 af[4], bfr[4];
        const int mrow = lane & 15;
        const int kq   = (lane >> 4) * 8;
        #pragma unroll
        for (int i = 0; i < 4; i++) {
            af[i]  = *(const bf16x8*)&As[(wr + i * 16 + mrow) * 32 + kq];
            bfr[i] = *(const bf16x8*)&Bs[(wc + i * 16 + mrow) * 32 + kq];
        }
        #pragma unroll
        for (int i = 0; i < 4; i++)
            #pragma unroll
            for (int j = 0; j < 4; j++)
                acc[i][j] = __builtin_amdgcn_mfma_f32_16x16x32_bf16(
                    af[i], bfr[j], acc[i][j], 0, 0, 0);
        __syncthreads();
    }

    const float* bp = z ? ((col0 < 128) ? b_attn : b_off) : b_val;
    const int cofs  = (z && col0 >= 128) ? 128 : 0;

    #pragma unroll
    for (int i = 0; i < 4; i++) {
        const int rbase = row0 + wr + i * 16 + ((lane >> 4) << 2);
        #pragma unroll
        for (int j = 0; j < 4; j++) {
            const int col = col0 + wc + j * 16 + (lane & 15);
            const float bb = bp[col - cofs];
            #pragma unroll
            for (int r = 0; r < 4; r++) {
                const int row = rbase + r;
                if (row < MREAL) {
                    const float val = acc[i][j][r] + bb;
                    if (z) lo_ws[(size_t)row * 384 + col] = val;
                    else   v_bf[(size_t)row * 256 + col] = f2bf(val);
                }
            }
        }
    }
}

// ---------------------------------------------------------------------------
// Out GEMM: out(MREAL,256) = mdv(bf16) @ wt_out^T + b_out (fp32 to d_out).
// ---------------------------------------------------------------------------
__global__ __launch_bounds__(256) void gemm_out(
    const ushortT* __restrict__ A, const ushortT* __restrict__ Bt,
    const float* __restrict__ bias, float* __restrict__ C)
{
    __shared__ __attribute__((aligned(16))) ushortT As[128 * 32];
    __shared__ __attribute__((aligned(16))) ushortT Bs[128 * 32];

    const int tid  = threadIdx.x;
    const int wave = tid >> 6;
    const int lane = tid & 63;
    const int row0 = blockIdx.y * 128;
    const int col0 = blockIdx.x * 128;
    const int wr = (wave >> 1) * 64;
    const int wc = (wave & 1) * 64;

    f32x4 acc[4][4];
    #pragma unroll
    for (int i = 0; i < 4; i++)
        #pragma unroll
        for (int j = 0; j < 4; j++)
            acc[i][j] = (f32x4)0.f;

    const int srow = (lane >> 2);
    const int sk8  = (lane & 3) * 8;

    for (int k0 = 0; k0 < 256; k0 += 32) {
        #pragma unroll
        for (int j = 0; j < 2; j++) {
            const int r = wave * 32 + j * 16;
            async_ld16(A  + (size_t)(row0 + r + srow) * 256 + k0 + sk8, &As[r * 32]);
            async_ld16(Bt + (size_t)(col0 + r + srow) * 256 + k0 + sk8, &Bs[r * 32]);
        }
        __syncthreads();

        bf16x8 af[4], bfr[4];
        const int mrow = lane & 15;
        const int kq   = (lane >> 4) * 8;
        #pragma unroll
        for (int i = 0; i < 4; i++) {
            af[i]  = *(const bf16x8*)&As[(wr + i * 16 + mrow) * 32 + kq];
            bfr[i] = *(const bf16x8*)&Bs[(wc + i * 16 + mrow) * 32 + kq];
        }
        #pragma unroll
        for (int i = 0; i < 4; i++)
            #pragma unroll
            for (int j = 0; j < 4; j++)
                acc[i][j] = __builtin_amdgcn_mfma_f32_16x16x32_bf16(
                    af[i], bfr[j], acc[i][j], 0, 0, 0);
        __syncthreads();
    }

    #pragma unroll
    for (int i = 0; i < 4; i++) {
        const int rbase = row0 + wr + i * 16 + ((lane >> 4) << 2);
        #pragma unroll
        for (int j = 0; j < 4; j++) {
            const int col = col0 + wc + j * 16 + (lane & 15);
            const float bb = bias[col];
            #pragma unroll
            for (int r = 0; r < 4; r++) {
                const int row = rbase + r;
                if (row < MREAL)
                    C[(size_t)row * 256 + col] = acc[i][j][r] + bb;
            }
        }
    }
}

// ---------------------------------------------------------------------------
// Two-phase sample kernel, wave-owns-query. Block = 4 waves = 4 queries.
// Phase 1 (lane=(m,p)): softmax via shfl over 8 p-lanes; per point emit ONE
//   16B record {base_byte_off, dx|dyrow<<16, half2 w01, half2 w23} (weights
//   pre-scaled by attn, zeroed for invalid corners, addresses clamped).
// Phase 2 (lane=(m,c)): per point 1x ds_read_b128 (bank-staggered, 2-way max),
//   4x 8B gathers, 8 unpack ops + 16 FMAs over 4 channels.
// LDS: 4 queries x 8 m x 68 dwords = 8704 B.
// ---------------------------------------------------------------------------
__global__ __launch_bounds__(256) void sample_kernel(
    const float* __restrict__ lo,       // (N*Q, 384): [0,128) logits, [128,384) off
    const float* __restrict__ geom,     // (N*Q, 4)
    const ushortT* __restrict__ v,      // (N*S, 256) bf16
    ushortT* __restrict__ out)          // (N*Q, 256) bf16 mdv
{
    const int tid  = threadIdx.x;
    const int w    = tid >> 6;          // wave = query offset
    const int lane = tid & 63;
    const int m    = lane >> 3;         // head, same in both phases
    const int n    = blockIdx.y;
    const int q0   = blockIdx.x << 2;

    __shared__ __attribute__((aligned(16))) int pls[4][544];   // 8704 B

    const size_t qb = (size_t)n * QN + q0 + w;

    // ---- phase 1 ----
    {
        const int p = lane & 7;                  // point pair 0..7
        const float* lorow = lo + qb * 384;
        const float2 lg = *(const float2*)(lorow + m * 16 + p * 2);
        const float4 of = *(const float4*)(lorow + 128 + m * 32 + p * 4);
        const float4 g  = *(const float4*)(geom + qb * 4);

        float mx = fmaxf(lg.x, lg.y);
        mx = fmaxf(mx, __shfl_xor(mx, 1));
        mx = fmaxf(mx, __shfl_xor(mx, 2));
        mx = fmaxf(mx, __shfl_xor(mx, 4));
        const float e0 = __expf(lg.x - mx);
        const float e1 = __expf(lg.y - mx);
        float s = e0 + e1;
        s += __shfl_xor(s, 1);
        s += __shfl_xor(s, 2);
        s += __shfl_xor(s, 4);
        const float inv = 1.f / s;

        const int l  = p >> 1;
        const int Wl = 96 >> l;
        const int s0 = (l == 0) ? 0 : (l == 1) ? 9216 : (l == 2) ? 11520 : 12096;
        const float cx = g.x, cy = g.y;
        const float sx = g.z * 0.125f, sy = g.w * 0.125f;
        int* myrec = &pls[w][m * 68 + p * 8];

        #pragma unroll
        for (int t = 0; t < 2; t++) {
            const float ox = t ? of.z : of.x;
            const float oy = t ? of.w : of.y;
            const float wa = (t ? e1 : e0) * inv;

            const float x = (cx + ox * sx) * (float)Wl - 0.5f;
            const float y = (cy + oy * sy) * (float)Wl - 0.5f;
            const float xf = floorf(x), yf = floorf(y);
            const int x0 = (int)xf, y0 = (int)yf;
            const float wx = x - xf, wy = y - yf;

            const bool vx0 = (x0 >= 0) & (x0 < Wl);
            const bool vx1 = (x0 + 1 >= 0) & (x0 + 1 < Wl);
            const bool vy0 = (y0 >= 0) & (y0 < Wl);
            const bool vy1 = (y0 + 1 >= 0) & (y0 + 1 < Wl);

            const float w00 = (vx0 & vy0) ? wa * (1.f - wx) * (1.f - wy) : 0.f;
            const float w10 = (vx1 & vy0) ? wa * wx * (1.f - wy) : 0.f;
            const float w01 = (vx0 & vy1) ? wa * (1.f - wx) * wy : 0.f;
            const float w11 = (vx1 & vy1) ? wa * wx * wy : 0.f;

            const int xc0 = min(max(x0, 0), Wl - 1);
            const int xc1 = min(max(x0 + 1, 0), Wl - 1);
            const int yc0 = min(max(y0, 0), Wl - 1);
            const int yc1 = min(max(y0 + 1, 0), Wl - 1);

            const int iv0   = (s0 + yc0 * Wl + xc0) << 9;   // byte offset, row 512B
            const int dx    = (xc1 - xc0) << 9;             // 0 or 512
            const int dyrow = ((yc1 - yc0) * Wl) << 9;      // 0..49152
            __half2 h01 = __floats2half2_rn(w00, w10);
            __half2 h23 = __floats2half2_rn(w01, w11);
            int4 rec;
            rec.x = iv0;
            rec.y = dx | (dyrow << 16);
            rec.z = *reinterpret_cast<int*>(&h01);
            rec.w = *reinterpret_cast<int*>(&h23);
            *(int4*)(myrec + t * 4) = rec;
        }
    }
    __syncthreads();

    // ---- phase 2 ----
    const int c = lane & 7;
    const int chan_byte = (m * 32 + c * 4) * 2;
    const unsigned char* vb =
        (const unsigned char*)(v + (size_t)n * SN * 256);
    const int* grec = &pls[w][m * 68];

    float a0 = 0.f, a1 = 0.f, a2 = 0.f, a3 = 0.f;

    #pragma unroll
    for (int lk = 0; lk < 16; lk++) {
        const int4 rec = *(const int4*)(grec + lk * 4);
        const int base = rec.x + chan_byte;
        const int dx   = rec.y & 0xffff;
        const int dy   = ((uintT)rec.y) >> 16;

        const uint2 u0 = *(const uint2*)(vb + base);
        const uint2 u1 = *(const uint2*)(vb + base + dx);
        const uint2 u2 = *(const uint2*)(vb + base + dy);
        const uint2 u3 = *(const uint2*)(vb + base + dy + dx);

        const __half2 h01 = *reinterpret_cast<const __half2*>(&rec.z);
        const __half2 h23 = *reinterpret_cast<const __half2*>(&rec.w);
        const float2 wlo = __half22float2(h01);
        const float2 whi = __half22float2(h23);

        a0 += wlo.x * bf_lo(u0.x) + wlo.y * bf_lo(u1.x) + whi.x * bf_lo(u2.x) + whi.y * bf_lo(u3.x);
        a1 += wlo.x * bf_hi(u0.x) + wlo.y * bf_hi(u1.x) + whi.x * bf_hi(u2.x) + whi.y * bf_hi(u3.x);
        a2 += wlo.x * bf_lo(u0.y) + wlo.y * bf_lo(u1.y) + whi.x * bf_lo(u2.y) + whi.y * bf_lo(u3.y);
        a3 += wlo.x * bf_hi(u0.y) + wlo.y * bf_hi(u1.y) + whi.x * bf_hi(u2.y) + whi.y * bf_hi(u3.y);
    }

    ushort4 o;
    o.x = f2bf(a0); o.y = f2bf(a1); o.z = f2bf(a2); o.w = f2bf(a3);
    *(ushort4*)(out + qb * 256 + m * 32 + c * 4) = o;
}

// ---------------------------------------------------------------------------
extern "C" void kernel_launch(void* const* d_in, const int* in_sizes, int n_in,
                              void* d_out, int out_size, void* d_ws, size_t ws_size,
                              hipStream_t stream)
{
    const float* queries = (const float*)d_in[0];
    const float* geom    = (const float*)d_in[1];
    const float* src     = (const float*)d_in[2];
    const float* W_off   = (const float*)d_in[3];
    const float* b_off   = (const float*)d_in[4];
    const float* W_attn  = (const float*)d_in[5];
    const float* b_attn  = (const float*)d_in[6];
    const float* W_val   = (const float*)d_in[7];
    const float* b_val   = (const float*)d_in[8];
    const float* W_out   = (const float*)d_in[9];
    const float* b_out   = (const float*)d_in[10];
    float* out = (float*)d_out;

    ushortT* wsb = (ushortT*)d_ws;
    const size_t PADROW = (size_t)MPAD * 256;          // 6,291,456 elems
    ushortT* q_bf    = wsb;
    ushortT* srcmdv  = wsb + PADROW;                   // src_bf, later mdv_bf
    ushortT* v_bf    = wsb + 2 * PADROW;
    ushortT* wt_val  = wsb + 3 * PADROW;               // 256*256
    ushortT* wt_lo   = wt_val + 65536;                 // 384*256
    ushortT* wt_out  = wt_lo + 98304;                  // 256*256
    float* lo_ws = (float*)(wt_out + 65536);           // 24480*384 fp32
    // total ~75.8 MB

    dim3 blk(256);

    cast_all<<<dim3(7016), blk, 0, stream>>>(
        queries, src, W_val, W_attn, W_off, W_out,
        q_bf, srcmdv, wt_val, wt_lo, wt_out);

    // bx<2: v = src@W_val -> v_bf (bf16); bx>=2: lo = q@[W_attn;W_off] -> lo_ws
    gemm_vlo<<<dim3(5, MT), blk, 0, stream>>>(
        q_bf, srcmdv, wt_val, wt_lo, b_val, b_attn, b_off, v_bf, lo_ws);

    sample_kernel<<<dim3(QN / 4, NB), blk, 0, stream>>>(
        lo_ws, geom, v_bf, srcmdv);

    gemm_out<<<dim3(2, MT), blk, 0, stream>>>(srcmdv, wt_out, b_out, out);
}